// Round 3
// baseline (116.555 us; speedup 1.0000x reference)
//
#include <hip/hip_runtime.h>
#include <hip/hip_fp16.h>
#include <stdint.h>

typedef float f32x4 __attribute__((ext_vector_type(4)));
typedef _Float16 f16x8 __attribute__((ext_vector_type(8)));
typedef unsigned short us8 __attribute__((ext_vector_type(8)));
typedef unsigned long long u64t;

#define N_PTS 32768
#define K_CB  1024
#define D_DIM 64
#define EPS   1.5e-3f
#define NSHARD 32
#define FCAP  8192

// ws layout (bytes):
#define WS_TOKEN 0        // int[32768]
#define WS_BDIST 131072   // float[32768]
#define WS_X2    262144   // float[32768]
#define WS_PCB   393216   // ushort[65536] fp16 frag-linear codebook
#define WS_CBT   524288   // float[65536]  cb transposed [d][c]
#define WS_C2    786432   // float[1024]
#define WS_SHARD 790528   // u32[32*1024]
#define WS_MIND  921600   // u32[1024]
#define WS_ACT   925696   // int[1024]
#define WS_FLAG  929792   // int[8192]
#define WS_FCNT  962560   // u32[64]
#define WS_DPART 962816   // float[64]

__device__ __forceinline__ void gld16(const void* g, void* l) {
    __builtin_amdgcn_global_load_lds(
        (const __attribute__((address_space(1))) unsigned int*)g,
        (__attribute__((address_space(3))) unsigned int*)l,
        16, 0, 0);
}

__device__ __forceinline__ float hi_f(u64t v) {
    return __uint_as_float((unsigned)(v >> 32));
}

// ---------------- k0: init + codebook preprocessing ----------------
__global__ __launch_bounds__(256) void vq_k0(const float* __restrict__ cb,
                                             unsigned* __restrict__ shard,
                                             int* __restrict__ active,
                                             float* __restrict__ c2,
                                             unsigned short* __restrict__ pcb,
                                             float* __restrict__ cbT,
                                             unsigned* __restrict__ fcnt) {
    int g = blockIdx.x * 256 + threadIdx.x;   // grid 64 -> 16384 threads
    shard[g] = 0x7F800000u;
    shard[g + 16384] = 0x7F800000u;
    if (g < 64) fcnt[g] = 0;
    if (g < K_CB) {
        active[g] = 0;
        const float4* row = (const float4*)(cb + g * 64);
        float s = 0.f;
#pragma unroll
        for (int q = 0; q < 16; ++q) {
            float4 v = row[q];
            s = fmaf(v.x, v.x, s); s = fmaf(v.y, v.y, s);
            s = fmaf(v.z, v.z, s); s = fmaf(v.w, v.w, s);
        }
        c2[g] = s;
    }
    if (g < 8192) {   // fp16 frag-linear: unit = (code c, 8-elem d-chunk u)
        int c = g >> 3, u = g & 7;
        const float4* row = (const float4*)(cb + c * 64);
        float4 v0 = row[u * 2], v1 = row[u * 2 + 1];
        us8 o;
        o[0] = __half_as_ushort(__float2half_rn(v0.x));
        o[1] = __half_as_ushort(__float2half_rn(v0.y));
        o[2] = __half_as_ushort(__float2half_rn(v0.z));
        o[3] = __half_as_ushort(__float2half_rn(v0.w));
        o[4] = __half_as_ushort(__float2half_rn(v1.x));
        o[5] = __half_as_ushort(__float2half_rn(v1.y));
        o[6] = __half_as_ushort(__float2half_rn(v1.z));
        o[7] = __half_as_ushort(__float2half_rn(v1.w));
        int frag  = (c >> 4) * 2 + (u >> 2);
        int lane8 = (c & 15) + 16 * (u & 3);
        *(us8*)&pcb[frag * 512 + lane8 * 8] = o;
    }
    {   // transpose: cbT[d][c] = cb[c][d]
        int c = g & 1023, seg = g >> 10;       // seg < 16, 4 d's each
        float4 v = ((const float4*)(cb + c * 64))[seg];
        cbT[(seg * 4 + 0) * 1024 + c] = v.x;
        cbT[(seg * 4 + 1) * 1024 + c] = v.y;
        cbT[(seg * 4 + 2) * 1024 + c] = v.z;
        cbT[(seg * 4 + 3) * 1024 + c] = v.w;
    }
}

// ---------------- k1: fp16-MFMA dists, top-2 argmin, per-code mins ----------------
__global__ __launch_bounds__(256, 3) void vq_k1(const float* __restrict__ x,
                                                const float* __restrict__ c2g,
                                                const unsigned short* __restrict__ pcb,
                                                unsigned* __restrict__ shard,
                                                int* __restrict__ token,
                                                float* __restrict__ bdist,
                                                float* __restrict__ x2a,
                                                int* __restrict__ gflag,
                                                unsigned* __restrict__ fcnt) {
    __shared__ __align__(16) unsigned short aF[4096];       // 8KB fp16 x-frags
    __shared__ __align__(16) unsigned short cbF[2][8192];   // 2x16KB fp16 code tiles
    __shared__ float c2s[1024];
    __shared__ float x2s[64];
    __shared__ u64t  wred[256];
    __shared__ float wm2[256];

    const int tid  = threadIdx.x;
    const int lane = tid & 63;
    const int w    = tid >> 6;
    const int p0   = blockIdx.x * 64;

    // issue first tile stage immediately (overlaps with conversion VALU)
    {
        const char* src = ((const char*)pcb);
        char* dst = (char*)&cbF[0][0];
#pragma unroll
        for (int it = 0; it < 4; ++it)
            gld16(src + it * 4096 + w * 1024 + (size_t)lane * 16,
                  dst + it * 4096 + w * 1024 + lane * 16);
    }

    // stage x -> fp16 frag-linear + exact-ish x2 (thread: row=tid>>2, 16 elems at 16*(tid&3))
    {
        int r = tid >> 2, sg = tid & 3;
        const float4* xr4 = (const float4*)(x + (size_t)(p0 + r) * 64) + sg * 4;
        float4 v0 = xr4[0], v1 = xr4[1], v2 = xr4[2], v3 = xr4[3];
        float s = 0.f;
        s = fmaf(v0.x, v0.x, s); s = fmaf(v0.y, v0.y, s); s = fmaf(v0.z, v0.z, s); s = fmaf(v0.w, v0.w, s);
        s = fmaf(v1.x, v1.x, s); s = fmaf(v1.y, v1.y, s); s = fmaf(v1.z, v1.z, s); s = fmaf(v1.w, v1.w, s);
        s = fmaf(v2.x, v2.x, s); s = fmaf(v2.y, v2.y, s); s = fmaf(v2.z, v2.z, s); s = fmaf(v2.w, v2.w, s);
        s = fmaf(v3.x, v3.x, s); s = fmaf(v3.y, v3.y, s); s = fmaf(v3.z, v3.z, s); s = fmaf(v3.w, v3.w, s);
        s += __shfl_xor(s, 1);
        s += __shfl_xor(s, 2);
        if (sg == 0) { x2s[r] = s; x2a[p0 + r] = s; }

        us8 o0, o1;
        o0[0]=__half_as_ushort(__float2half_rn(v0.x)); o0[1]=__half_as_ushort(__float2half_rn(v0.y));
        o0[2]=__half_as_ushort(__float2half_rn(v0.z)); o0[3]=__half_as_ushort(__float2half_rn(v0.w));
        o0[4]=__half_as_ushort(__float2half_rn(v1.x)); o0[5]=__half_as_ushort(__float2half_rn(v1.y));
        o0[6]=__half_as_ushort(__float2half_rn(v1.z)); o0[7]=__half_as_ushort(__float2half_rn(v1.w));
        o1[0]=__half_as_ushort(__float2half_rn(v2.x)); o1[1]=__half_as_ushort(__float2half_rn(v2.y));
        o1[2]=__half_as_ushort(__float2half_rn(v2.z)); o1[3]=__half_as_ushort(__float2half_rn(v2.w));
        o1[4]=__half_as_ushort(__float2half_rn(v3.x)); o1[5]=__half_as_ushort(__float2half_rn(v3.y));
        o1[6]=__half_as_ushort(__float2half_rn(v3.z)); o1[7]=__half_as_ushort(__float2half_rn(v3.w));
        int u0 = 2 * sg, u1 = 2 * sg + 1;
        int f0 = (r >> 4) * 2 + (u0 >> 2), l0 = (r & 15) + 16 * (u0 & 3);
        int f1 = (r >> 4) * 2 + (u1 >> 2), l1 = (r & 15) + 16 * (u1 & 3);
        *(us8*)&aF[f0 * 512 + l0 * 8] = o0;
        *(us8*)&aF[f1 * 512 + l1 * 8] = o1;
    }
#pragma unroll
    for (int q = 0; q < 4; ++q) c2s[tid + q * 256] = c2g[tid + q * 256];
    __syncthreads();   // aF/x2s/c2s ready; tile-0 stage drained

    f16x8 a[4][2];
#pragma unroll
    for (int rf = 0; rf < 4; ++rf)
#pragma unroll
        for (int kk = 0; kk < 2; ++kk)
            a[rf][kk] = *(const f16x8*)&aF[(rf * 2 + kk) * 512 + lane * 8];

    float x2r[16];
#pragma unroll
    for (int rf = 0; rf < 4; ++rf)
#pragma unroll
        for (int i = 0; i < 4; ++i)
            x2r[rf * 4 + i] = x2s[rf * 16 + (lane >> 4) * 4 + i];

    u64t  m1[16];
    float m2[16];
#pragma unroll
    for (int r = 0; r < 16; ++r) { m1[r] = 0x7F800000FFFFFFFFull; m2[r] = 3.4e38f; }

    const unsigned shbase = (blockIdx.x & (NSHARD - 1)) << 10;

    for (int t = 0; t < 8; ++t) {
        const int cur = t & 1;
        if (t < 7) {   // prefetch next tile
            const char* src = ((const char*)pcb) + (t + 1) * 16384;
            char* dst = (char*)&cbF[cur ^ 1][0];
#pragma unroll
            for (int it = 0; it < 4; ++it)
                gld16(src + it * 4096 + w * 1024 + (size_t)lane * 16,
                      dst + it * 4096 + w * 1024 + lane * 16);
        }

        f32x4 acc[4][2];
#pragma unroll
        for (int rf = 0; rf < 4; ++rf)
#pragma unroll
            for (int cf = 0; cf < 2; ++cf)
                acc[rf][cf] = (f32x4){0.f, 0.f, 0.f, 0.f};

#pragma unroll
        for (int cf = 0; cf < 2; ++cf)
#pragma unroll
            for (int kk = 0; kk < 2; ++kk) {
                f16x8 b = *(const f16x8*)&cbF[cur][(((cf * 4 + w) * 2) + kk) * 512 + lane * 8];
#pragma unroll
                for (int rf = 0; rf < 4; ++rf)
                    acc[rf][cf] = __builtin_amdgcn_mfma_f32_16x16x32_f16(
                        a[rf][kk], b, acc[rf][cf], 0, 0, 0);
            }

        // epilogue: dist, top-2 per point-row, per-code min
#pragma unroll
        for (int cf = 0; cf < 2; ++cf) {
            const unsigned cg = t * 128 + (cf * 4 + w) * 16 + (lane & 15);
            const float c2v = c2s[cg];
            float pcm = 3.4e38f;
#pragma unroll
            for (int rf = 0; rf < 4; ++rf)
#pragma unroll
                for (int i = 0; i < 4; ++i) {
                    const int r = rf * 4 + i;
                    float d = fmaf(-2.0f, acc[rf][cf][i], x2r[r]) + c2v;
                    u64t pk = ((u64t)__float_as_uint(d) << 32) | cg;
                    float prev = hi_f(m1[r]);
                    m2[r] = fminf(m2[r], fmaxf(d, prev));
                    if (pk < m1[r]) m1[r] = pk;
                    pcm = fminf(pcm, d);
                }
            pcm = fminf(pcm, __shfl_xor(pcm, 16));
            pcm = fminf(pcm, __shfl_xor(pcm, 32));
            if (lane < 16) atomicMin(&shard[shbase + cg], __float_as_uint(pcm));
        }
        __syncthreads();   // tile cur fully consumed; prefetch drained
    }

    // merge top-2 across the 16 code-lanes
#pragma unroll
    for (int s = 1; s < 16; s <<= 1) {
#pragma unroll
        for (int r = 0; r < 16; ++r) {
            u64t o = __shfl_xor(m1[r], s);
            float om2 = __shfl_xor(m2[r], s);
            float lose = fmaxf(hi_f(m1[r]), hi_f(o));
            m2[r] = fminf(fminf(m2[r], om2), lose);
            if (o < m1[r]) m1[r] = o;
        }
    }
    if ((lane & 15) == 0) {
#pragma unroll
        for (int rf = 0; rf < 4; ++rf)
#pragma unroll
            for (int i = 0; i < 4; ++i) {
                int grow = rf * 16 + (lane >> 4) * 4 + i;
                wred[w * 64 + grow] = m1[rf * 4 + i];
                wm2[w * 64 + grow]  = m2[rf * 4 + i];
            }
    }
    __syncthreads();
    if (tid < 64) {
        u64t b = wred[tid];
        float mm2 = wm2[tid];
#pragma unroll
        for (int q = 1; q < 4; ++q) {
            u64t o = wred[q * 64 + tid];
            float om2 = wm2[q * 64 + tid];
            float lose = fmaxf(hi_f(b), hi_f(o));
            mm2 = fminf(fminf(mm2, om2), lose);
            if (o < b) b = o;
        }
        float bd = hi_f(b);
        int p = p0 + tid;
        token[p] = (int)(unsigned)(b & 0xFFFFFFFFu);
        bdist[p] = bd;
        if (mm2 - bd <= EPS) {   // near-tie: needs exact resolution
            unsigned ix = atomicAdd(fcnt, 1u);
            if (ix < FCAP) gflag[ix] = p;
        }
    }
}

// ---------------- k_fix: exact fp32 rescan for flagged points ----------------
__global__ __launch_bounds__(256) void vq_kfix(const float* __restrict__ x,
                                               const float* __restrict__ cbT,
                                               const float* __restrict__ c2,
                                               const float* __restrict__ x2a,
                                               const int* __restrict__ gflag,
                                               const unsigned* __restrict__ fcnt,
                                               int* __restrict__ token,
                                               float* __restrict__ bdist) {
    __shared__ float xl[64];
    __shared__ u64t red[256];
    const int tid = threadIdx.x;
    unsigned nf = fcnt[0]; if (nf > FCAP) nf = FCAP;

    for (unsigned fi = blockIdx.x; fi < nf; fi += gridDim.x) {
        int p = gflag[fi];
        if (tid < 64) xl[tid] = x[(size_t)p * 64 + tid];
        __syncthreads();
        float x2v = x2a[p];
        float s0 = 0.f, s1 = 0.f, s2 = 0.f, s3 = 0.f;
#pragma unroll
        for (int d = 0; d < 64; ++d) {
            float xv = xl[d];
            s0 = fmaf(xv, cbT[d * 1024 +   0 + tid], s0);
            s1 = fmaf(xv, cbT[d * 1024 + 256 + tid], s1);
            s2 = fmaf(xv, cbT[d * 1024 + 512 + tid], s2);
            s3 = fmaf(xv, cbT[d * 1024 + 768 + tid], s3);
        }
        u64t bb = ~0ull;
        float d0 = (x2v - 2.f * s0) + c2[tid];
        float d1 = (x2v - 2.f * s1) + c2[tid + 256];
        float d2 = (x2v - 2.f * s2) + c2[tid + 512];
        float d3 = (x2v - 2.f * s3) + c2[tid + 768];
        u64t pk;
        pk = ((u64t)__float_as_uint(d0) << 32) | (unsigned)(tid);       if (pk < bb) bb = pk;
        pk = ((u64t)__float_as_uint(d1) << 32) | (unsigned)(tid + 256); if (pk < bb) bb = pk;
        pk = ((u64t)__float_as_uint(d2) << 32) | (unsigned)(tid + 512); if (pk < bb) bb = pk;
        pk = ((u64t)__float_as_uint(d3) << 32) | (unsigned)(tid + 768); if (pk < bb) bb = pk;
        red[tid] = bb;
        __syncthreads();
        for (int s = 128; s > 0; s >>= 1) {
            if (tid < s) { u64t o = red[tid + s]; if (o < red[tid]) red[tid] = o; }
            __syncthreads();
        }
        if (tid == 0) {
            u64t b = red[0];
            token[p] = (int)(unsigned)(b & 0xFFFFFFFFu);
            bdist[p] = hi_f(b);
        }
        __syncthreads();
    }
}

// ---------------- k2: straight-through output + active histogram ----------------
__global__ __launch_bounds__(256) void vq_k2(const float* __restrict__ x,
                                             const float* __restrict__ cb,
                                             const int* __restrict__ token,
                                             int* __restrict__ active,
                                             float* __restrict__ out) {
    int g = blockIdx.x * 256 + threadIdx.x;
    int p = g >> 4, q = g & 15;
    int tok = token[p];
    if (q == 0) atomicAdd(&active[tok], 1);
    float4 xv = reinterpret_cast<const float4*>(x)[g];
    float4 cv = reinterpret_cast<const float4*>(cb)[tok * 16 + q];
    float4 o;
    o.x = xv.x + (cv.x - xv.x);
    o.y = xv.y + (cv.y - xv.y);
    o.z = xv.z + (cv.z - xv.z);
    o.w = xv.w + (cv.w - xv.w);
    reinterpret_cast<float4*>(out)[g] = o;
}

// ---------------- k3a: merge shards ----------------
__global__ __launch_bounds__(256) void vq_k3a(const unsigned* __restrict__ shard,
                                              unsigned* __restrict__ minDist) {
    int c = blockIdx.x * 256 + threadIdx.x;   // grid 4
    unsigned m = 0x7F800000u;
#pragma unroll
    for (int s = 0; s < NSHARD; ++s) m = min(m, shard[s * 1024 + c]);
    minDist[c] = m;
}

// ---------------- k3b: partial sums of bdist ----------------
__global__ __launch_bounds__(256) void vq_k3b(const float* __restrict__ bdist,
                                              float* __restrict__ dpart) {
    __shared__ float red[256];
    const int tid = threadIdx.x;
    const float4* base = (const float4*)(bdist + blockIdx.x * 2048);   // grid 16
    float4 v0 = base[tid * 2], v1 = base[tid * 2 + 1];
    red[tid] = ((v0.x + v0.y) + (v0.z + v0.w)) + ((v1.x + v1.y) + (v1.z + v1.w));
    __syncthreads();
    for (int s = 128; s > 0; s >>= 1) {
        if (tid < s) red[tid] += red[tid + s];
        __syncthreads();
    }
    if (tid == 0) dpart[blockIdx.x] = red[0];
}

// ---------------- k3: final loss ----------------
__global__ __launch_bounds__(1024) void vq_k3(const unsigned* __restrict__ minDist,
                                              const int* __restrict__ active,
                                              const float* __restrict__ dpart,
                                              float* __restrict__ out_loss) {
    __shared__ double red[1024];
    __shared__ double entS;
    int t = threadIdx.x;

    red[t] = (active[t] == 0) ? (double)__uint_as_float(minDist[t]) : 0.0;
    __syncthreads();
    for (int s = 512; s > 0; s >>= 1) {
        if (t < s) red[t] += red[t + s];
        __syncthreads();
    }
    if (t == 0) entS = red[0];
    __syncthreads();

    red[t] = (t < 16) ? (double)dpart[t] : 0.0;
    __syncthreads();
    for (int s = 512; s > 0; s >>= 1) {
        if (t < s) red[t] += red[t + s];
        __syncthreads();
    }
    if (t == 0) {
        double mean_sq = red[0] / (double)((long long)N_PTS * D_DIM);
        double total = 1.25 * mean_sq + 0.01 * (entS / (double)K_CB);
        out_loss[0] = (float)total;
    }
}

extern "C" void kernel_launch(void* const* d_in, const int* in_sizes, int n_in,
                              void* d_out, int out_size, void* d_ws, size_t ws_size,
                              hipStream_t stream) {
    const float* x  = (const float*)d_in[0];
    const float* cb = (const float*)d_in[1];
    float* out = (float*)d_out;
    char* ws = (char*)d_ws;

    int*            token   = (int*)(ws + WS_TOKEN);
    float*          bdist   = (float*)(ws + WS_BDIST);
    float*          x2a     = (float*)(ws + WS_X2);
    unsigned short* pcb     = (unsigned short*)(ws + WS_PCB);
    float*          cbT     = (float*)(ws + WS_CBT);
    float*          c2      = (float*)(ws + WS_C2);
    unsigned*       shard   = (unsigned*)(ws + WS_SHARD);
    unsigned*       minDist = (unsigned*)(ws + WS_MIND);
    int*            active  = (int*)(ws + WS_ACT);
    int*            gflag   = (int*)(ws + WS_FLAG);
    unsigned*       fcnt    = (unsigned*)(ws + WS_FCNT);
    float*          dpart   = (float*)(ws + WS_DPART);

    vq_k0  <<<64,   256, 0, stream>>>(cb, shard, active, c2, pcb, cbT, fcnt);
    vq_k1  <<<512,  256, 0, stream>>>(x, c2, pcb, shard, token, bdist, x2a, gflag, fcnt);
    vq_kfix<<<512,  256, 0, stream>>>(x, cbT, c2, x2a, gflag, fcnt, token, bdist);
    vq_k2  <<<2048, 256, 0, stream>>>(x, cb, token, active, out);
    vq_k3a <<<4,    256, 0, stream>>>(shard, minDist);
    vq_k3b <<<16,   256, 0, stream>>>(bdist, dpart);
    vq_k3  <<<1,   1024, 0, stream>>>(minDist, active, dpart, out + 2097152);
}